// Round 15
// baseline (377.419 us; speedup 1.0000x reference)
//
#include <hip/hip_runtime.h>
#include <hip/hip_bf16.h>
#include <cstdint>
#include <cstddef>

#define NSAMP  64
#define NPT    16384
#define NLVL   4
#define NCHUNK 8
#define CHSZ   (NPT / NCHUNK)   // 2048 points per chunk

typedef __attribute__((ext_vector_type(8))) short  short8;
typedef __attribute__((ext_vector_type(4))) float  floatx4;
typedef __attribute__((ext_vector_type(4))) unsigned int uintx4;
typedef __attribute__((ext_vector_type(2))) unsigned int uintx2;

// fp32 -> bf16 RNE (finite values only)
__device__ __forceinline__ unsigned short f2bf(float x) {
    union { float f; unsigned int u; } c; c.f = x;
    unsigned int r = (c.u + 0x7fffu + ((c.u >> 16) & 1u)) >> 16;
    return (unsigned short)r;
}
__device__ __forceinline__ unsigned int f2bf2(float a, float b) {
    __hip_bfloat162 t = __float22bfloat162_rn(make_float2(a, b));
    union { __hip_bfloat162 h; unsigned int u; } c; c.h = t;
    return c.u;
}

// ---------------------------------------------------------------------------
// Kernel 0: fold BatchNorm into weights/bias (unchanged).
// Layer 1 stays FP32 (accuracy: bf16 layer-1 inputs cost 13x absmax, round 4).
// ---------------------------------------------------------------------------
__global__ __launch_bounds__(256) void prep_kernel(
    const float* __restrict__ w1, const float* __restrict__ b1, const float* __restrict__ g1,
    const float* __restrict__ be1, const float* __restrict__ m1, const float* __restrict__ v1,
    const float* __restrict__ w2, const float* __restrict__ b2, const float* __restrict__ g2,
    const float* __restrict__ be2, const float* __restrict__ m2, const float* __restrict__ v2,
    const float* __restrict__ w3, const float* __restrict__ b3, const float* __restrict__ g3,
    const float* __restrict__ be3, const float* __restrict__ m3, const float* __restrict__ v3,
    float* __restrict__ w1f, float* __restrict__ fb1,
    unsigned short* __restrict__ w2b, float* __restrict__ fb2,
    unsigned short* __restrict__ w3b, float* __restrict__ fb3)
{
    const int t  = blockIdx.x * 256 + threadIdx.x;
    const int nt = gridDim.x * 256;
    const float eps = 1e-5f;
    for (int i = t; i < 64 * 3; i += nt)    w1f[i] = w1[i] * (g1[i / 3] / sqrtf(v1[i / 3] + eps));
    for (int i = t; i < 64; i += nt)        fb1[i] = (b1[i] - m1[i]) * (g1[i] / sqrtf(v1[i] + eps)) + be1[i];
    for (int i = t; i < 128 * 64; i += nt)  w2b[i] = f2bf(w2[i] * (g2[i / 64] / sqrtf(v2[i / 64] + eps)));
    for (int i = t; i < 128; i += nt)       fb2[i] = (b2[i] - m2[i]) * (g2[i] / sqrtf(v2[i] + eps)) + be2[i];
    for (int i = t; i < 256 * 128; i += nt) w3b[i] = f2bf(w3[i] * (g3[i / 128] / sqrtf(v3[i / 128] + eps)));
    for (int i = t; i < 256; i += nt)       fb3[i] = (b3[i] - m3[i]) * (g3[i] / sqrtf(v3[i] + eps)) + be3[i];
}

// ---------------------------------------------------------------------------
// Kernel 1: LDS-staged chunked scan (r10/r12 version — stable).
// ---------------------------------------------------------------------------
__global__ __launch_bounds__(512) void scan_kernel(
    const float* __restrict__ seedp, const float* __restrict__ pc,
    const float* __restrict__ rot, unsigned short* __restrict__ buf,
    int* __restrict__ cnts)
{
    __shared__ float ch[CHSZ * 3];                 // 24576 B
    const int tid  = threadIdx.x;
    const int lane = tid & 63;
    const int w    = tid >> 6;                     // 0..7
    const int sg   = blockIdx.x >> 3;              // seed group 0..255
    const int c    = blockIdx.x & 7;               // chunk
    const int g    = sg * 8 + w;                   // seed 0..2047
    const int b    = g >> 10;

    {
        const float4* src = (const float4*)(pc + ((size_t)b * NPT + c * CHSZ) * 3);
        float4* dst = (float4*)ch;
        dst[tid]        = src[tid];
        dst[tid + 512]  = src[tid + 512];
        dst[tid + 1024] = src[tid + 1024];
    }
    __syncthreads();

    const float* sd = seedp + (size_t)g * 3;
    const float sx = sd[0], sy = sd[1], sz = sd[2];
    const float* R = rot + (size_t)g * 9;
    const float r00 = R[0], r01 = R[1], r02 = R[2];
    const float r10 = R[3], r11 = R[4], r12 = R[5];
    const float r20 = R[6], r21 = R[7], r22 = R[8];
    const float nc0 = -(sx * r00 + sy * r10 + sz * r20);
    const float nc1 = -(sx * r01 + sy * r11 + sz * r21);
    const float nc2 = -(sx * r02 + sy * r12 + sz * r22);

    unsigned short* bufg = buf + (size_t)g * (NLVL * NCHUNK * 64);
    int cnt0 = 0, cnt1 = 0, cnt2 = 0, cnt3 = 0;
    const unsigned long long lm = (1ull << lane) - 1ull;

    for (int bt = 0; bt < 4; ++bt) {               // 4 batches x 8 iters
        float pxv[8], pyv[8], pzv[8];
        #pragma unroll
        for (int j = 0; j < 8; ++j) {              // 24 LDS loads, batched
            const int pl = (bt * 8 + j) * 64 + lane;
            pxv[j] = ch[pl * 3];
            pyv[j] = ch[pl * 3 + 1];
            pzv[j] = ch[pl * 3 + 2];
        }
        #pragma unroll
        for (int j = 0; j < 8; ++j) {              // pure-VALU tests
            const float h = fmaf(pxv[j], r00, fmaf(pyv[j], r10, fmaf(pzv[j], r20, nc0)));
            const float u = fmaf(pxv[j], r01, fmaf(pyv[j], r11, fmaf(pzv[j], r21, nc1)));
            const float v = fmaf(pxv[j], r02, fmaf(pyv[j], r12, fmaf(pzv[j], r22, nc2)));
            const float r2 = fmaf(u, u, v * v);
            const bool base = (r2 < 0.0025f) && (h > -0.02f) && (h < 0.04f);

            const unsigned long long bal3 = __ballot(base);
            if (bal3 == 0ull) continue;            // ~97% of iterations

            const unsigned short pidx = (unsigned short)(c * CHSZ + (bt * 8 + j) * 64 + lane);
            #pragma unroll
            for (int l = 0; l < NLVL; ++l) {
                unsigned long long bal; bool m;
                if (l == 3) { m = base; bal = bal3; }
                else {
                    const float hm = (l == 0) ? 0.01f : (l == 1) ? 0.02f : 0.03f;
                    m = base && (h < hm);
                    bal = __ballot(m);
                }
                int& cnt = (l == 0) ? cnt0 : (l == 1) ? cnt1 : (l == 2) ? cnt2 : cnt3;
                if (m) {
                    const int pos = cnt + (int)__popcll(bal & lm);
                    if (pos < 64) bufg[(l * NCHUNK + c) * 64 + pos] = pidx;
                }
                cnt += (int)__popcll(bal);
            }
        }
        if (cnt0 >= NSAMP) break;                  // nested: level 0 fills last
    }

    if (lane == 0) {
        int* cg = cnts + (size_t)g * (NLVL * NCHUNK);
        cg[0 * NCHUNK + c] = cnt0;
        cg[1 * NCHUNK + c] = cnt1;
        cg[2 * NCHUNK + c] = cnt2;
        cg[3 * NCHUNK + c] = cnt3;
    }
}

// ---------------------------------------------------------------------------
// Kernel 1b: gather (r9/r12 version — stable).
// ---------------------------------------------------------------------------
__global__ __launch_bounds__(256) void gather_kernel(
    const float* __restrict__ seedp, const float* __restrict__ pc,
    const float* __restrict__ rot,
    const unsigned short* __restrict__ buf, const int* __restrict__ cnts,
    float* __restrict__ gx)
{
    const int n = threadIdx.x & 63;
    const int W = blockIdx.x * 4 + (threadIdx.x >> 6);   // 0..8191
    const int g = W >> 2, l = W & 3;
    const int b = g >> 10;

    const int* cg = cnts + (size_t)g * (NLVL * NCHUNK) + l * NCHUNK;
    const unsigned short* bl = buf + (size_t)g * (NLVL * NCHUNK * 64) + l * (NCHUNK * 64);
    int idx = -1, acc = 0, firstIdx = -1;
    #pragma unroll
    for (int c = 0; c < NCHUNK; ++c) {
        const int cn = min(cg[c], 64);
        if (cn > 0 && firstIdx < 0) firstIdx = (int)bl[c * 64];
        if (n >= acc && n < acc + cn) idx = (int)bl[c * 64 + (n - acc)];
        acc += cn;
    }
    if (idx < 0) idx = (firstIdx >= 0) ? firstIdx : 0;

    const float* sd = seedp + (size_t)g * 3;
    const float* R  = rot   + (size_t)g * 9;
    const float* pp = pc + ((size_t)b * NPT + idx) * 3;
    const float dx = pp[0] - sd[0], dy = pp[1] - sd[1], dz = pp[2] - sd[2];

    float* o = gx + (size_t)W * 192;
    o[n]       = dx * R[0] + dy * R[3] + dz * R[6];
    o[64 + n]  = dx * R[1] + dy * R[4] + dz * R[7];
    o[128 + n] = dx * R[2] + dy * R[5] + dz * R[8];
}

// ---------------------------------------------------------------------------
// Kernel 2: MLP + max-pool. ROUND 15: REGISTER-PRESSURE DIET for occupancy.
// mlp was 33% stalled at 19% occupancy (VGPR 112 -> 4 waves/SIMD). Live-set
// cuts (target <= 102 VGPR -> 5 waves/SIMD, enforced by launch_bounds):
//  - W3 no longer register-cached for the whole block: streamed per mt with
//    single-buffer prefetch (32 regs peak vs 64). L1/L2-hot (same 64 KB
//    table every block/iteration).
//  - L3 split into two nt-halves (samples 0-31 / 32-63) with partial-max
//    merge (exact: max associative). bfr3 halves 64 -> 32 regs. LDS-read
//    and MFMA counts unchanged (16 b128, 64 MFMA per iter).
//  - W2/b2 loads moved inside the iteration (kills loop-spanning live regs).
// Keeps r14's pipelined L1 (it+1 overlaps L3), 2 barriers/iter, 4 groups/blk.
// ---------------------------------------------------------------------------
__global__ __launch_bounds__(256, 5) void mlp_kernel(
    const float* __restrict__ gx,
    const float* __restrict__ w1f, const float* __restrict__ fb1,
    const unsigned short* __restrict__ w2b, const float* __restrict__ fb2,
    const unsigned short* __restrict__ w3b, const float* __restrict__ fb3,
    float* __restrict__ out)
{
    __shared__ unsigned short h1t[4096];           // [8][64][8]    8 KB
    __shared__ unsigned short h2t[8192];           // [16][64][8]  16 KB

    const int tid = threadIdx.x;
    const int n      = tid & 63;                   // sample (= lane)
    const int w      = tid >> 6;
    const int lane15 = tid & 15;
    const int quad   = (tid & 63) >> 4;

    // ---- Layer-1 prologue (it = 0)
    {
        const float* xb = gx + (size_t)(blockIdx.x * 4) * 192;
        const float x0 = xb[n], x1 = xb[64 + n], x2 = xb[128 + n];
        unsigned int p[8];
        #pragma unroll
        for (int j = 0; j < 8; ++j) {
            const int o0 = __builtin_amdgcn_readfirstlane(w * 16 + 2 * j);
            const float a0 = fb1[o0]     + w1f[o0*3]*x0   + w1f[o0*3+1]*x1 + w1f[o0*3+2]*x2;
            const float a1 = fb1[o0 + 1] + w1f[o0*3+3]*x0 + w1f[o0*3+4]*x1 + w1f[o0*3+5]*x2;
            p[j] = f2bf2(fmaxf(a0, 0.f), fmaxf(a1, 0.f));
        }
        *(uintx4*)&h1t[(((w * 2)    ) * 64 + n) * 8] = (uintx4){p[0], p[1], p[2], p[3]};
        *(uintx4*)&h1t[(((w * 2) + 1) * 64 + n) * 8] = (uintx4){p[4], p[5], p[6], p[7]};
    }

    for (int it = 0; it < 4; ++it) {
        const int gp = blockIdx.x * 4 + it;        // 0..8191
        const int g = gp >> 2, l = gp & 3;
        const int b = g >> 10, s = g & 1023;

        __syncthreads();   // h1t(it) visible; prior h2t reads drained

        // ---- Layer 2: 64 -> 128 (MFMA); weights streamed (L1-hot)
        {
            short8 bfr[4][2];
            #pragma unroll
            for (int nt = 0; nt < 4; ++nt)
                #pragma unroll
                for (int k0 = 0; k0 < 2; ++k0)
                    bfr[nt][k0] = *(const short8*)&h1t[((k0 * 4 + quad) * 64 + nt * 16 + lane15) * 8];

            #pragma unroll
            for (int mi = 0; mi < 2; ++mi) {
                const int m0 = (w * 2 + mi) * 16;
                const short8 a0 = *(const short8*)&w2b[(m0 + lane15) * 64 + quad * 8];
                const short8 a1 = *(const short8*)&w2b[(m0 + lane15) * 64 + 32 + quad * 8];
                const floatx4 bv = *(const floatx4*)&fb2[m0 + quad * 4];
                #pragma unroll
                for (int nt = 0; nt < 4; ++nt) {
                    floatx4 acc = bv;
                    acc = __builtin_amdgcn_mfma_f32_16x16x32_bf16(a0, bfr[nt][0], acc, 0, 0, 0);
                    acc = __builtin_amdgcn_mfma_f32_16x16x32_bf16(a1, bfr[nt][1], acc, 0, 0, 0);
                    const int n2 = nt * 16 + lane15;
                    const unsigned int q0 = f2bf2(fmaxf(acc[0], 0.f), fmaxf(acc[1], 0.f));
                    const unsigned int q1 = f2bf2(fmaxf(acc[2], 0.f), fmaxf(acc[3], 0.f));
                    const int kb = (m0 >> 3) + (quad >> 1);
                    *(uintx2*)&h2t[(kb * 64 + n2) * 8 + (quad & 1) * 4] = (uintx2){q0, q1};
                }
            }
        }
        __syncthreads();   // h2t(it) visible; h1t(it) reads drained

        // ---- Layer 1 for it+1 (overlaps L3; h1t free after barrier-2)
        if (it < 3) {
            const float* xb = gx + (size_t)(gp + 1) * 192;
            const float x0 = xb[n], x1 = xb[64 + n], x2 = xb[128 + n];
            unsigned int p[8];
            #pragma unroll
            for (int j = 0; j < 8; ++j) {
                const int o0 = __builtin_amdgcn_readfirstlane(w * 16 + 2 * j);
                const float a0 = fb1[o0]     + w1f[o0*3]*x0   + w1f[o0*3+1]*x1 + w1f[o0*3+2]*x2;
                const float a1 = fb1[o0 + 1] + w1f[o0*3+3]*x0 + w1f[o0*3+4]*x1 + w1f[o0*3+5]*x2;
                p[j] = f2bf2(fmaxf(a0, 0.f), fmaxf(a1, 0.f));
            }
            *(uintx4*)&h1t[(((w * 2)    ) * 64 + n) * 8] = (uintx4){p[0], p[1], p[2], p[3]};
            *(uintx4*)&h1t[(((w * 2) + 1) * 64 + n) * 8] = (uintx4){p[4], p[5], p[6], p[7]};
        }

        // ---- Layer 3: 128 -> 256 TRANSPOSED, nt-split halves, streamed W3
        float tmax[4] = {-3.4e38f, -3.4e38f, -3.4e38f, -3.4e38f};
        #pragma unroll
        for (int half = 0; half < 2; ++half) {
            short8 bfr3[2][4];
            #pragma unroll
            for (int ntl = 0; ntl < 2; ++ntl) {
                const int nt = half * 2 + ntl;
                #pragma unroll
                for (int k0 = 0; k0 < 4; ++k0)
                    bfr3[ntl][k0] = *(const short8*)&h2t[((k0 * 4 + quad) * 64 + nt * 16 + lane15) * 8];
            }
            short8 wf[4];
            #pragma unroll
            for (int k0 = 0; k0 < 4; ++k0)
                wf[k0] = *(const short8*)&w3b[((w * 4) * 16 + lane15) * 128 + k0 * 32 + quad * 8];

            #pragma unroll
            for (int mt = 0; mt < 4; ++mt) {
                short8 wc[4];
                #pragma unroll
                for (int k0 = 0; k0 < 4; ++k0) wc[k0] = wf[k0];
                if (mt < 3) {   // single-buffer prefetch of next mt's frags
                    const int m0n = (w * 4 + mt + 1) * 16;
                    #pragma unroll
                    for (int k0 = 0; k0 < 4; ++k0)
                        wf[k0] = *(const short8*)&w3b[(m0n + lane15) * 128 + k0 * 32 + quad * 8];
                }
                floatx4 acc0 = (floatx4){0.f, 0.f, 0.f, 0.f};
                floatx4 acc1 = (floatx4){0.f, 0.f, 0.f, 0.f};
                #pragma unroll
                for (int k0 = 0; k0 < 4; ++k0) {   // D = H * W^T (operands swapped)
                    acc0 = __builtin_amdgcn_mfma_f32_16x16x32_bf16(bfr3[0][k0], wc[k0], acc0, 0, 0, 0);
                    acc1 = __builtin_amdgcn_mfma_f32_16x16x32_bf16(bfr3[1][k0], wc[k0], acc1, 0, 0, 0);
                }
                const float t0 = fmaxf(fmaxf(acc0[0], acc0[1]), fmaxf(acc0[2], acc0[3]));
                const float t1 = fmaxf(fmaxf(acc1[0], acc1[1]), fmaxf(acc1[2], acc1[3]));
                tmax[mt] = fmaxf(tmax[mt], fmaxf(t0, t1));
            }
        }

        // ---- epilogue: cross-quad max, bias post-max (exact), ReLU, store
        #pragma unroll
        for (int mt = 0; mt < 4; ++mt) {
            float t = tmax[mt];
            t = fmaxf(t, __shfl_xor(t, 16));
            t = fmaxf(t, __shfl_xor(t, 32));
            if (quad == 0) {
                const int o = (w * 4 + mt) * 16 + lane15;
                out[(((size_t)b * 256 + o) * 1024 + s) * 4 + l] = fmaxf(t + fb3[o], 0.f);
            }
        }
    }
}

// ---------------------------------------------------------------------------
// Workspace: w1f fl[192] fb1 fl[64] fb2 fl[128] fb3 fl[256]
//            w2b us[8192] w3b us[32768]
//            buf us[4,194,304] cnts int[65,536]
//            gx  fl[1,572,864]                     (~15 MB)
// ---------------------------------------------------------------------------
extern "C" void kernel_launch(void* const* d_in, const int* in_sizes, int n_in,
                              void* d_out, int out_size, void* d_ws, size_t ws_size,
                              hipStream_t stream) {
    const float* seed = (const float*)d_in[0];
    const float* pc   = (const float*)d_in[1];
    const float* rot  = (const float*)d_in[2];
    const float* w1 = (const float*)d_in[3];
    const float* b1 = (const float*)d_in[4];
    const float* g1 = (const float*)d_in[5];
    const float* be1 = (const float*)d_in[6];
    const float* m1 = (const float*)d_in[7];
    const float* v1 = (const float*)d_in[8];
    const float* w2 = (const float*)d_in[9];
    const float* b2 = (const float*)d_in[10];
    const float* g2 = (const float*)d_in[11];
    const float* be2 = (const float*)d_in[12];
    const float* m2 = (const float*)d_in[13];
    const float* v2 = (const float*)d_in[14];
    const float* w3 = (const float*)d_in[15];
    const float* b3 = (const float*)d_in[16];
    const float* g3 = (const float*)d_in[17];
    const float* be3 = (const float*)d_in[18];
    const float* m3 = (const float*)d_in[19];
    const float* v3 = (const float*)d_in[20];

    float* w1f = (float*)d_ws;                            // 192
    float* fb1 = w1f + 192;                               // 64
    float* fb2 = fb1 + 64;                                // 128
    float* fb3 = fb2 + 128;                               // 256
    unsigned short* w2b = (unsigned short*)(fb3 + 256);   // 8192
    unsigned short* w3b = w2b + 8192;                     // 32768
    unsigned short* buf = w3b + 32768;                    // 4,194,304
    int* cnts = (int*)(buf + 4194304);                    // 65,536
    float* gx = (float*)(cnts + 65536);                   // 1,572,864

    prep_kernel<<<64, 256, 0, stream>>>(w1, b1, g1, be1, m1, v1,
                                        w2, b2, g2, be2, m2, v2,
                                        w3, b3, g3, be3, m3, v3,
                                        w1f, fb1, w2b, fb2, w3b, fb3);
    scan_kernel<<<2048, 512, 0, stream>>>(seed, pc, rot, buf, cnts);
    gather_kernel<<<2048, 256, 0, stream>>>(seed, pc, rot, buf, cnts, gx);
    mlp_kernel<<<2048, 256, 0, stream>>>(gx, w1f, fb1, w2b, fb2, w3b, fb3,
                                         (float*)d_out);
}

// Round 16
// 183.600 us; speedup vs baseline: 2.0557x; 2.0557x over previous
//
#include <hip/hip_runtime.h>
#include <hip/hip_bf16.h>
#include <cstdint>
#include <cstddef>

#define NSAMP  64
#define NPT    16384
#define NLVL   4
#define NCHUNK 8
#define CHSZ   (NPT / NCHUNK)   // 2048 points per chunk

typedef __attribute__((ext_vector_type(8))) short  short8;
typedef __attribute__((ext_vector_type(4))) float  floatx4;
typedef __attribute__((ext_vector_type(4))) unsigned int uintx4;
typedef __attribute__((ext_vector_type(2))) unsigned int uintx2;

// fp32 -> bf16 RNE (finite values only)
__device__ __forceinline__ unsigned short f2bf(float x) {
    union { float f; unsigned int u; } c; c.f = x;
    unsigned int r = (c.u + 0x7fffu + ((c.u >> 16) & 1u)) >> 16;
    return (unsigned short)r;
}
__device__ __forceinline__ unsigned int f2bf2(float a, float b) {
    __hip_bfloat162 t = __float22bfloat162_rn(make_float2(a, b));
    union { __hip_bfloat162 h; unsigned int u; } c; c.h = t;
    return c.u;
}

// ---------------------------------------------------------------------------
// Kernel 0: fold BatchNorm into weights/bias (unchanged).
// Layer 1 stays FP32 (accuracy: bf16 layer-1 inputs cost 13x absmax, round 4).
// ---------------------------------------------------------------------------
__global__ __launch_bounds__(256) void prep_kernel(
    const float* __restrict__ w1, const float* __restrict__ b1, const float* __restrict__ g1,
    const float* __restrict__ be1, const float* __restrict__ m1, const float* __restrict__ v1,
    const float* __restrict__ w2, const float* __restrict__ b2, const float* __restrict__ g2,
    const float* __restrict__ be2, const float* __restrict__ m2, const float* __restrict__ v2,
    const float* __restrict__ w3, const float* __restrict__ b3, const float* __restrict__ g3,
    const float* __restrict__ be3, const float* __restrict__ m3, const float* __restrict__ v3,
    float* __restrict__ w1f, float* __restrict__ fb1,
    unsigned short* __restrict__ w2b, float* __restrict__ fb2,
    unsigned short* __restrict__ w3b, float* __restrict__ fb3)
{
    const int t  = blockIdx.x * 256 + threadIdx.x;
    const int nt = gridDim.x * 256;
    const float eps = 1e-5f;
    for (int i = t; i < 64 * 3; i += nt)    w1f[i] = w1[i] * (g1[i / 3] / sqrtf(v1[i / 3] + eps));
    for (int i = t; i < 64; i += nt)        fb1[i] = (b1[i] - m1[i]) * (g1[i] / sqrtf(v1[i] + eps)) + be1[i];
    for (int i = t; i < 128 * 64; i += nt)  w2b[i] = f2bf(w2[i] * (g2[i / 64] / sqrtf(v2[i / 64] + eps)));
    for (int i = t; i < 128; i += nt)       fb2[i] = (b2[i] - m2[i]) * (g2[i] / sqrtf(v2[i] + eps)) + be2[i];
    for (int i = t; i < 256 * 128; i += nt) w3b[i] = f2bf(w3[i] * (g3[i / 128] / sqrtf(v3[i / 128] + eps)));
    for (int i = t; i < 256; i += nt)       fb3[i] = (b3[i] - m3[i]) * (g3[i] / sqrtf(v3[i] + eps)) + be3[i];
}

// ---------------------------------------------------------------------------
// Kernel 1: LDS-staged chunked scan (r10/r12 version — stable).
// ---------------------------------------------------------------------------
__global__ __launch_bounds__(512) void scan_kernel(
    const float* __restrict__ seedp, const float* __restrict__ pc,
    const float* __restrict__ rot, unsigned short* __restrict__ buf,
    int* __restrict__ cnts)
{
    __shared__ float ch[CHSZ * 3];                 // 24576 B
    const int tid  = threadIdx.x;
    const int lane = tid & 63;
    const int w    = tid >> 6;                     // 0..7
    const int sg   = blockIdx.x >> 3;              // seed group 0..255
    const int c    = blockIdx.x & 7;               // chunk
    const int g    = sg * 8 + w;                   // seed 0..2047
    const int b    = g >> 10;

    {
        const float4* src = (const float4*)(pc + ((size_t)b * NPT + c * CHSZ) * 3);
        float4* dst = (float4*)ch;
        dst[tid]        = src[tid];
        dst[tid + 512]  = src[tid + 512];
        dst[tid + 1024] = src[tid + 1024];
    }
    __syncthreads();

    const float* sd = seedp + (size_t)g * 3;
    const float sx = sd[0], sy = sd[1], sz = sd[2];
    const float* R = rot + (size_t)g * 9;
    const float r00 = R[0], r01 = R[1], r02 = R[2];
    const float r10 = R[3], r11 = R[4], r12 = R[5];
    const float r20 = R[6], r21 = R[7], r22 = R[8];
    const float nc0 = -(sx * r00 + sy * r10 + sz * r20);
    const float nc1 = -(sx * r01 + sy * r11 + sz * r21);
    const float nc2 = -(sx * r02 + sy * r12 + sz * r22);

    unsigned short* bufg = buf + (size_t)g * (NLVL * NCHUNK * 64);
    int cnt0 = 0, cnt1 = 0, cnt2 = 0, cnt3 = 0;
    const unsigned long long lm = (1ull << lane) - 1ull;

    for (int bt = 0; bt < 4; ++bt) {               // 4 batches x 8 iters
        float pxv[8], pyv[8], pzv[8];
        #pragma unroll
        for (int j = 0; j < 8; ++j) {              // 24 LDS loads, batched
            const int pl = (bt * 8 + j) * 64 + lane;
            pxv[j] = ch[pl * 3];
            pyv[j] = ch[pl * 3 + 1];
            pzv[j] = ch[pl * 3 + 2];
        }
        #pragma unroll
        for (int j = 0; j < 8; ++j) {              // pure-VALU tests
            const float h = fmaf(pxv[j], r00, fmaf(pyv[j], r10, fmaf(pzv[j], r20, nc0)));
            const float u = fmaf(pxv[j], r01, fmaf(pyv[j], r11, fmaf(pzv[j], r21, nc1)));
            const float v = fmaf(pxv[j], r02, fmaf(pyv[j], r12, fmaf(pzv[j], r22, nc2)));
            const float r2 = fmaf(u, u, v * v);
            const bool base = (r2 < 0.0025f) && (h > -0.02f) && (h < 0.04f);

            const unsigned long long bal3 = __ballot(base);
            if (bal3 == 0ull) continue;            // ~97% of iterations

            const unsigned short pidx = (unsigned short)(c * CHSZ + (bt * 8 + j) * 64 + lane);
            #pragma unroll
            for (int l = 0; l < NLVL; ++l) {
                unsigned long long bal; bool m;
                if (l == 3) { m = base; bal = bal3; }
                else {
                    const float hm = (l == 0) ? 0.01f : (l == 1) ? 0.02f : 0.03f;
                    m = base && (h < hm);
                    bal = __ballot(m);
                }
                int& cnt = (l == 0) ? cnt0 : (l == 1) ? cnt1 : (l == 2) ? cnt2 : cnt3;
                if (m) {
                    const int pos = cnt + (int)__popcll(bal & lm);
                    if (pos < 64) bufg[(l * NCHUNK + c) * 64 + pos] = pidx;
                }
                cnt += (int)__popcll(bal);
            }
        }
        if (cnt0 >= NSAMP) break;                  // nested: level 0 fills last
    }

    if (lane == 0) {
        int* cg = cnts + (size_t)g * (NLVL * NCHUNK);
        cg[0 * NCHUNK + c] = cnt0;
        cg[1 * NCHUNK + c] = cnt1;
        cg[2 * NCHUNK + c] = cnt2;
        cg[3 * NCHUNK + c] = cnt3;
    }
}

// ---------------------------------------------------------------------------
// Kernel 1b: gather (r9/r12 version — stable).
// ---------------------------------------------------------------------------
__global__ __launch_bounds__(256) void gather_kernel(
    const float* __restrict__ seedp, const float* __restrict__ pc,
    const float* __restrict__ rot,
    const unsigned short* __restrict__ buf, const int* __restrict__ cnts,
    float* __restrict__ gx)
{
    const int n = threadIdx.x & 63;
    const int W = blockIdx.x * 4 + (threadIdx.x >> 6);   // 0..8191
    const int g = W >> 2, l = W & 3;
    const int b = g >> 10;

    const int* cg = cnts + (size_t)g * (NLVL * NCHUNK) + l * NCHUNK;
    const unsigned short* bl = buf + (size_t)g * (NLVL * NCHUNK * 64) + l * (NCHUNK * 64);
    int idx = -1, acc = 0, firstIdx = -1;
    #pragma unroll
    for (int c = 0; c < NCHUNK; ++c) {
        const int cn = min(cg[c], 64);
        if (cn > 0 && firstIdx < 0) firstIdx = (int)bl[c * 64];
        if (n >= acc && n < acc + cn) idx = (int)bl[c * 64 + (n - acc)];
        acc += cn;
    }
    if (idx < 0) idx = (firstIdx >= 0) ? firstIdx : 0;

    const float* sd = seedp + (size_t)g * 3;
    const float* R  = rot   + (size_t)g * 9;
    const float* pp = pc + ((size_t)b * NPT + idx) * 3;
    const float dx = pp[0] - sd[0], dy = pp[1] - sd[1], dz = pp[2] - sd[2];

    float* o = gx + (size_t)W * 192;
    o[n]       = dx * R[0] + dy * R[3] + dz * R[6];
    o[64 + n]  = dx * R[1] + dy * R[4] + dz * R[7];
    o[128 + n] = dx * R[2] + dy * R[5] + dz * R[8];
}

// ---------------------------------------------------------------------------
// Kernel 2: MLP + max-pool. ROUND 16 = exact REVERT to round 14 (best
// verified: mlp 70.2 us, VGPR 112, no spills). r15's launch_bounds(256,5)
// register diet forced ~1 GB/dispatch scratch spill traffic (FETCH 543 MB)
// — the L3 live set structurally needs ~112 VGPR; 4 waves/SIMD is the cap.
//  - h1t/h2t un-aliased (24 KB): 2 barriers/iter.
//  - Layer 1 of it+1 overlaps L3 MFMA of it (pipelined).
//  - W2 fragments + b2 hoisted (loop-invariant); W3 + b3 register-cached.
//  - Transposed L3 (D = H*W^T) + in-register max + 2 shfl_xor epilogue.
// ---------------------------------------------------------------------------
__global__ __launch_bounds__(256) void mlp_kernel(
    const float* __restrict__ gx,
    const float* __restrict__ w1f, const float* __restrict__ fb1,
    const unsigned short* __restrict__ w2b, const float* __restrict__ fb2,
    const unsigned short* __restrict__ w3b, const float* __restrict__ fb3,
    float* __restrict__ out)
{
    __shared__ unsigned short h1t[4096];           // [8][64][8]    8 KB
    __shared__ unsigned short h2t[8192];           // [16][64][8]  16 KB

    const int tid = threadIdx.x;
    const int n      = tid & 63;                   // sample (= lane)
    const int w      = tid >> 6;
    const int lane15 = tid & 15;
    const int quad   = (tid & 63) >> 4;

    // ---- cache ALL layer-3 weights + bias in registers (once per block)
    short8 wa3[4][4];
    float  wb3[4];
    #pragma unroll
    for (int mt = 0; mt < 4; ++mt) {
        const int m0 = (w * 4 + mt) * 16;
        #pragma unroll
        for (int k0 = 0; k0 < 4; ++k0)
            wa3[mt][k0] = *(const short8*)&w3b[(m0 + lane15) * 128 + k0 * 32 + quad * 8];
        wb3[mt] = fb3[m0 + lane15];
    }

    // ---- cache layer-2 weight fragments (loop-invariant)
    short8 a20[2], a21[2]; floatx4 b2v[2];
    #pragma unroll
    for (int mi = 0; mi < 2; ++mi) {
        const int m0 = (w * 2 + mi) * 16;
        a20[mi] = *(const short8*)&w2b[(m0 + lane15) * 64 + quad * 8];
        a21[mi] = *(const short8*)&w2b[(m0 + lane15) * 64 + 32 + quad * 8];
        b2v[mi] = *(const floatx4*)&fb2[m0 + quad * 4];
    }

    // ---- Layer-1 prologue (it = 0)
    {
        const float* xb = gx + (size_t)(blockIdx.x * 4) * 192;
        const float x0 = xb[n], x1 = xb[64 + n], x2 = xb[128 + n];
        unsigned int p[8];
        #pragma unroll
        for (int j = 0; j < 8; ++j) {
            const int o0 = __builtin_amdgcn_readfirstlane(w * 16 + 2 * j);
            const float a0 = fb1[o0]     + w1f[o0*3]*x0   + w1f[o0*3+1]*x1 + w1f[o0*3+2]*x2;
            const float a1 = fb1[o0 + 1] + w1f[o0*3+3]*x0 + w1f[o0*3+4]*x1 + w1f[o0*3+5]*x2;
            p[j] = f2bf2(fmaxf(a0, 0.f), fmaxf(a1, 0.f));
        }
        *(uintx4*)&h1t[(((w * 2)    ) * 64 + n) * 8] = (uintx4){p[0], p[1], p[2], p[3]};
        *(uintx4*)&h1t[(((w * 2) + 1) * 64 + n) * 8] = (uintx4){p[4], p[5], p[6], p[7]};
    }

    for (int it = 0; it < 4; ++it) {
        const int gp = blockIdx.x * 4 + it;        // 0..8191
        const int g = gp >> 2, l = gp & 3;
        const int b = g >> 10, s = g & 1023;

        __syncthreads();   // h1t(it) visible; bfr3(it-1) h2t reads drained

        // ---- Layer 2: 64 -> 128 (MFMA). h1t -> regs -> MFMA -> h2t
        {
            short8 bfr[4][2];
            #pragma unroll
            for (int nt = 0; nt < 4; ++nt)
                #pragma unroll
                for (int k0 = 0; k0 < 2; ++k0)
                    bfr[nt][k0] = *(const short8*)&h1t[((k0 * 4 + quad) * 64 + nt * 16 + lane15) * 8];

            #pragma unroll
            for (int mi = 0; mi < 2; ++mi) {
                const int m0 = (w * 2 + mi) * 16;
                #pragma unroll
                for (int nt = 0; nt < 4; ++nt) {
                    floatx4 acc = b2v[mi];
                    acc = __builtin_amdgcn_mfma_f32_16x16x32_bf16(a20[mi], bfr[nt][0], acc, 0, 0, 0);
                    acc = __builtin_amdgcn_mfma_f32_16x16x32_bf16(a21[mi], bfr[nt][1], acc, 0, 0, 0);
                    const int n2 = nt * 16 + lane15;
                    const unsigned int q0 = f2bf2(fmaxf(acc[0], 0.f), fmaxf(acc[1], 0.f));
                    const unsigned int q1 = f2bf2(fmaxf(acc[2], 0.f), fmaxf(acc[3], 0.f));
                    const int kb = (m0 >> 3) + (quad >> 1);
                    *(uintx2*)&h2t[(kb * 64 + n2) * 8 + (quad & 1) * 4] = (uintx2){q0, q1};
                }
            }
        }
        __syncthreads();   // h2t(it) visible; h1t(it) reads drained

        // ---- Layer 3 fragment reads (h2t -> regs)
        short8 bfr3[4][4];
        #pragma unroll
        for (int nt = 0; nt < 4; ++nt)
            #pragma unroll
            for (int k0 = 0; k0 < 4; ++k0)
                bfr3[nt][k0] = *(const short8*)&h2t[((k0 * 4 + quad) * 64 + nt * 16 + lane15) * 8];

        // ---- Layer 1 for it+1 (overlaps L3 MFMA; h1t is free after barrier-2)
        if (it < 3) {
            const float* xb = gx + (size_t)(gp + 1) * 192;
            const float x0 = xb[n], x1 = xb[64 + n], x2 = xb[128 + n];
            unsigned int p[8];
            #pragma unroll
            for (int j = 0; j < 8; ++j) {
                const int o0 = __builtin_amdgcn_readfirstlane(w * 16 + 2 * j);
                const float a0 = fb1[o0]     + w1f[o0*3]*x0   + w1f[o0*3+1]*x1 + w1f[o0*3+2]*x2;
                const float a1 = fb1[o0 + 1] + w1f[o0*3+3]*x0 + w1f[o0*3+4]*x1 + w1f[o0*3+5]*x2;
                p[j] = f2bf2(fmaxf(a0, 0.f), fmaxf(a1, 0.f));
            }
            *(uintx4*)&h1t[(((w * 2)    ) * 64 + n) * 8] = (uintx4){p[0], p[1], p[2], p[3]};
            *(uintx4*)&h1t[(((w * 2) + 1) * 64 + n) * 8] = (uintx4){p[4], p[5], p[6], p[7]};
        }

        // ---- Layer 3: 128 -> 256 TRANSPOSED (D = H*W^T), fused max-pool
        #pragma unroll
        for (int mt = 0; mt < 4; ++mt) {
            const int m0 = (w * 4 + mt) * 16;    // channel block
            floatx4 acc[4];
            #pragma unroll
            for (int nt = 0; nt < 4; ++nt) acc[nt] = (floatx4){0.f, 0.f, 0.f, 0.f};
            #pragma unroll
            for (int k0 = 0; k0 < 4; ++k0)
                #pragma unroll
                for (int nt = 0; nt < 4; ++nt)   // OPERANDS SWAPPED: D = H * W^T
                    acc[nt] = __builtin_amdgcn_mfma_f32_16x16x32_bf16(bfr3[nt][k0], wa3[mt][k0], acc[nt], 0, 0, 0);

            float t0 = fmaxf(fmaxf(acc[0][0], acc[0][1]), fmaxf(acc[0][2], acc[0][3]));
            float t1 = fmaxf(fmaxf(acc[1][0], acc[1][1]), fmaxf(acc[1][2], acc[1][3]));
            float t2 = fmaxf(fmaxf(acc[2][0], acc[2][1]), fmaxf(acc[2][2], acc[2][3]));
            float t3 = fmaxf(fmaxf(acc[3][0], acc[3][1]), fmaxf(acc[3][2], acc[3][3]));
            float t  = fmaxf(fmaxf(t0, t1), fmaxf(t2, t3));
            t = fmaxf(t, __shfl_xor(t, 16));
            t = fmaxf(t, __shfl_xor(t, 32));
            if (quad == 0) {
                const int o = m0 + lane15;
                out[(((size_t)b * 256 + o) * 1024 + s) * 4 + l] = fmaxf(t + wb3[mt], 0.f);
            }
        }
    }
}

// ---------------------------------------------------------------------------
// Workspace: w1f fl[192] fb1 fl[64] fb2 fl[128] fb3 fl[256]
//            w2b us[8192] w3b us[32768]
//            buf us[4,194,304] cnts int[65,536]
//            gx  fl[1,572,864]                     (~15 MB)
// ---------------------------------------------------------------------------
extern "C" void kernel_launch(void* const* d_in, const int* in_sizes, int n_in,
                              void* d_out, int out_size, void* d_ws, size_t ws_size,
                              hipStream_t stream) {
    const float* seed = (const float*)d_in[0];
    const float* pc   = (const float*)d_in[1];
    const float* rot  = (const float*)d_in[2];
    const float* w1 = (const float*)d_in[3];
    const float* b1 = (const float*)d_in[4];
    const float* g1 = (const float*)d_in[5];
    const float* be1 = (const float*)d_in[6];
    const float* m1 = (const float*)d_in[7];
    const float* v1 = (const float*)d_in[8];
    const float* w2 = (const float*)d_in[9];
    const float* b2 = (const float*)d_in[10];
    const float* g2 = (const float*)d_in[11];
    const float* be2 = (const float*)d_in[12];
    const float* m2 = (const float*)d_in[13];
    const float* v2 = (const float*)d_in[14];
    const float* w3 = (const float*)d_in[15];
    const float* b3 = (const float*)d_in[16];
    const float* g3 = (const float*)d_in[17];
    const float* be3 = (const float*)d_in[18];
    const float* m3 = (const float*)d_in[19];
    const float* v3 = (const float*)d_in[20];

    float* w1f = (float*)d_ws;                            // 192
    float* fb1 = w1f + 192;                               // 64
    float* fb2 = fb1 + 64;                                // 128
    float* fb3 = fb2 + 128;                               // 256
    unsigned short* w2b = (unsigned short*)(fb3 + 256);   // 8192
    unsigned short* w3b = w2b + 8192;                     // 32768
    unsigned short* buf = w3b + 32768;                    // 4,194,304
    int* cnts = (int*)(buf + 4194304);                    // 65,536
    float* gx = (float*)(cnts + 65536);                   // 1,572,864

    prep_kernel<<<64, 256, 0, stream>>>(w1, b1, g1, be1, m1, v1,
                                        w2, b2, g2, be2, m2, v2,
                                        w3, b3, g3, be3, m3, v3,
                                        w1f, fb1, w2b, fb2, w3b, fb3);
    scan_kernel<<<2048, 512, 0, stream>>>(seed, pc, rot, buf, cnts);
    gather_kernel<<<2048, 256, 0, stream>>>(seed, pc, rot, buf, cnts, gx);
    mlp_kernel<<<2048, 256, 0, stream>>>(gx, w1f, fb1, w2b, fb2, w3b, fb3,
                                         (float*)d_out);
}